// Round 3
// baseline (299.513 us; speedup 1.0000x reference)
//
#include <hip/hip_runtime.h>
#include <hip/hip_bf16.h>
#include <stdint.h>

typedef _Float16 f16x8 __attribute__((ext_vector_type(8)));
typedef _Float16 f16x2 __attribute__((ext_vector_type(2)));
typedef float    f32x4 __attribute__((ext_vector_type(4)));

#define NPROTO 1024
#define EMB    512
#define NB     16
#define HW     4096           // 64*64
#define NPIX   (NB * HW)      // 65536
#define INV_TEMP 10.0f        // 1/0.1
#define TPX    64             // pixels per block
#define NTHR   1024           // 16 waves

// ---------------- prep: prototypes f32 -> fp16, pnorm = |p|^2 (exact f32) ----------------
__global__ void prep_protos(const float* __restrict__ proto,
                            _Float16* __restrict__ Ph,
                            float* __restrict__ pnorm) {
    int k = blockIdx.x;          // 1024 blocks
    int t = threadIdx.x;         // 64 threads, 1 wave
    const float* src = proto + (size_t)k * EMB + t * 8;
    float4 v0 = ((const float4*)src)[0];
    float4 v1 = ((const float4*)src)[1];
    float sq = v0.x*v0.x + v0.y*v0.y + v0.z*v0.z + v0.w*v0.w
             + v1.x*v1.x + v1.y*v1.y + v1.z*v1.z + v1.w*v1.w;
    f16x8 h;
    h[0] = (_Float16)v0.x; h[1] = (_Float16)v0.y; h[2] = (_Float16)v0.z; h[3] = (_Float16)v0.w;
    h[4] = (_Float16)v1.x; h[5] = (_Float16)v1.y; h[6] = (_Float16)v1.z; h[7] = (_Float16)v1.w;
    *(f16x8*)(Ph + (size_t)k * EMB + t * 8) = h;
#pragma unroll
    for (int m = 1; m < 64; m <<= 1) sq += __shfl_xor(sq, m);
    if (t == 0) pnorm[k] = sq;
}

__global__ void zero_counts(int* __restrict__ counts) {
    int i = blockIdx.x * blockDim.x + threadIdx.x;
    if (i < NB * NPROTO) counts[i] = 0;
}

// ---------------- main: GEMM (P * X^T) + dist + softmax + transposed write + argmax ----------------
// Block: 64 contiguous pixels x 1024 protos. 1024 thr = 16 waves; wave w owns protos
// [w*64, w*64+64) x all 64 px -> acc[4 mf][4 nf] of f32x4 (64 VGPR).
// A: [1024 k][32 c] fp16 rows of 64B, 4x16B slots XOR-swizzled (slot = cg ^ (k&3)),
//    double-buffered, filled by global_load_lds(16B) with PRE-SWIZZLED global source
//    (linear LDS dest, rule #21). B: [64 px][32 c] fp16, same swizzle, reg-staged
//    (f32 load -> cvt -> ds_write_b32), double-buffered. One barrier per K-step.
__global__ __launch_bounds__(NTHR)
void assign_main(const float* __restrict__ fm, const _Float16* __restrict__ Ph,
                 const float* __restrict__ pnorm, int* __restrict__ counts,
                 float* __restrict__ out) {
    __shared__ __align__(16) unsigned char smem[143360];
    unsigned char* Abuf = smem;                       // 2 x 65536
    unsigned char* Bbuf = smem + 131072;              // 2 x 4096
    float* pn           = (float*)(smem + 139264);    // 1024 f32 (live whole kernel)
    // epilogue aliases into the (dead) A region:
    float* redmax = (float*)(smem);                   // [16][64]
    float* redsum = (float*)(smem + 4096);
    float* argv_  = (float*)(smem + 8192);
    int*   argk_  = (int*)  (smem + 12288);
    float* xnsum  = (float*)(smem + 16384);           // [16][64]
    float* xn     = (float*)(smem + 20480);           // [64]

    const int t    = threadIdx.x;
    const int lane = t & 63, wid = t >> 6;
    const int lrow = lane >> 4;      // 0..3
    const int lcol = lane & 15;

    const int n0  = blockIdx.x * TPX;
    const int b   = n0 >> 12;            // image
    const int hw0 = n0 & 4095;

    pn[t] = pnorm[t];

    f32x4 acc[4][4];
#pragma unroll
    for (int i = 0; i < 4; ++i)
#pragma unroll
        for (int j = 0; j < 4; ++j)
#pragma unroll
            for (int e = 0; e < 4; ++e) acc[i][j][e] = 0.0f;

    // B staging assignment: thread -> (pixel bpx, channel pair bc)
    const int bpx = t & 63;
    const int bc  = (t >> 6) << 1;       // 0,2,..,30
    const float* fmB = fm + (size_t)b * EMB * HW + hw0 + bpx;
    float sq = 0.0f;                      // exact f32 |x|^2 partial (2 channels of bpx per step)
    float bv0, bv1;

    // A prefetch: pass p, wave wid: rows k in [p*256 + wid*16, +16), lane l -> (k=base+(l>>2), slot=l&3)
    // content channels cg = slot ^ (k&3)  (involution; read undoes it)
    auto stageA = [&](int cur, int ks) {
        const int c0 = ks * 32;
#pragma unroll
        for (int p = 0; p < 4; ++p) {
            int k  = p * 256 + wid * 16 + (lane >> 2);
            int cg = (lane & 3) ^ (k & 3);
            const _Float16* src = Ph + (size_t)k * EMB + c0 + cg * 8;
            __builtin_amdgcn_global_load_lds(
                (const __attribute__((address_space(1))) void*)src,
                (__attribute__((address_space(3))) void*)(Abuf + cur * 65536 + p * 16384 + wid * 1024),
                16, 0, 0);
        }
    };
    auto loadB = [&](int ks) {
        const float* p0 = fmB + (size_t)(ks * 32 + bc) * HW;
        bv0 = p0[0];
        bv1 = p0[HW];
    };
    auto writeB = [&](int cur) {
        sq += bv0 * bv0 + bv1 * bv1;
        f16x2 h; h[0] = (_Float16)bv0; h[1] = (_Float16)bv1;
        int slot = (bc >> 3) ^ (bpx & 3);
        *(f16x2*)(Bbuf + cur * 4096 + bpx * 64 + (slot << 4) + (bc & 7) * 2) = h;
    };

    // prologue: fill buffer 0
    stageA(0, 0);
    loadB(0);
    writeB(0);
    __syncthreads();          // compiler emits vmcnt(0) drain for global_load_lds here

    int cur = 0;
    for (int ks = 0; ks < 16; ++ks) {
        if (ks < 15) {                    // prefetch next tile (flies under the MFMAs)
            stageA(cur ^ 1, ks + 1);
            loadB(ks + 1);
        }
        f16x8 bf[4];
#pragma unroll
        for (int nf = 0; nf < 4; ++nf) {
            int px   = nf * 16 + lcol;
            int slot = lrow ^ (px & 3);
            bf[nf] = *(const f16x8*)(Bbuf + cur * 4096 + px * 64 + (slot << 4));
        }
#pragma unroll
        for (int mf = 0; mf < 4; ++mf) {
            int r    = wid * 64 + mf * 16 + lcol;
            int slot = lrow ^ (r & 3);
            f16x8 af = *(const f16x8*)(Abuf + cur * 65536 + r * 64 + (slot << 4));
#pragma unroll
            for (int nf = 0; nf < 4; ++nf)
                acc[mf][nf] = __builtin_amdgcn_mfma_f32_16x16x32_f16(af, bf[nf], acc[mf][nf], 0, 0, 0);
        }
        if (ks < 15) writeB(cur ^ 1);     // after vmcnt wait on bv (data dep)
        __syncthreads();
        cur ^= 1;
    }

    // ---- xnorm: [16 channel-groups][64 px] partials -> xn[64] ----
    xnsum[(t >> 6) * 64 + bpx] = sq;
    __syncthreads();
    if (t < 64) {
        float s = 0.0f;
#pragma unroll
        for (int g = 0; g < 16; ++g) s += xnsum[g * 64 + t];
        xn[t] = s;
    }
    __syncthreads();

    // ---- logits = -10*sqrt(max(|x|^2+|p|^2-2x.p, 0)); local max/argmax ----
    float xnv[4];
#pragma unroll
    for (int nf = 0; nf < 4; ++nf) xnv[nf] = xn[nf * 16 + lcol];

    float lmax[4] = {-1e30f, -1e30f, -1e30f, -1e30f};
    float lav[4]  = {-1e30f, -1e30f, -1e30f, -1e30f};
    int   lak[4]  = {0, 0, 0, 0};
#pragma unroll
    for (int mf = 0; mf < 4; ++mf) {
#pragma unroll
        for (int nf = 0; nf < 4; ++nf) {
#pragma unroll
            for (int j = 0; j < 4; ++j) {
                int kidx = wid * 64 + mf * 16 + lrow * 4 + j;   // ascending in (mf,j)
                float d2 = xnv[nf] + pn[kidx] - 2.0f * acc[mf][nf][j];
                float lg = -INV_TEMP * sqrtf(fmaxf(d2, 0.0f));
                acc[mf][nf][j] = lg;
                if (lg > lav[nf]) { lav[nf] = lg; lak[nf] = kidx; }  // strict > => first index
                lmax[nf] = fmaxf(lmax[nf], lg);
            }
        }
    }
    // reduce across the 4 lane-groups (same px column): xor 16, 32
#pragma unroll
    for (int nf = 0; nf < 4; ++nf) {
#pragma unroll
        for (int m = 16; m <= 32; m <<= 1) {
            float ov = __shfl_xor(lav[nf], m);
            int   ok = __shfl_xor(lak[nf], m);
            if (ov > lav[nf] || (ov == lav[nf] && ok < lak[nf])) { lav[nf] = ov; lak[nf] = ok; }
            lmax[nf] = fmaxf(lmax[nf], __shfl_xor(lmax[nf], m));
        }
    }
    if (lane < 16) {
#pragma unroll
        for (int nf = 0; nf < 4; ++nf) {
            int idx = wid * 64 + nf * 16 + lane;
            redmax[idx] = lmax[nf];
            argv_[idx]  = lav[nf];
            argk_[idx]  = lak[nf];
        }
    }
    __syncthreads();

    // ---- global max/argmax over 16 waves (ascending wave = ascending k); exp + partial sums ----
    float gmax[4];
#pragma unroll
    for (int nf = 0; nf < 4; ++nf) {
        int px = nf * 16 + lcol;
        float gm = -1e30f, gav = -1e30f;
        int gak = 0;
#pragma unroll
        for (int w = 0; w < 16; ++w) {
            gm = fmaxf(gm, redmax[w * 64 + px]);
            float av = argv_[w * 64 + px];
            int   ak = argk_[w * 64 + px];
            if (av > gav || (av == gav && ak < gak)) { gav = av; gak = ak; }
        }
        gmax[nf] = gm;
        if (wid == 0 && lane < 16) atomicAdd(&counts[b * NPROTO + gak], 1);

        float s = 0.0f;
#pragma unroll
        for (int mf = 0; mf < 4; ++mf)
#pragma unroll
            for (int j = 0; j < 4; ++j) {
                float e = __expf(acc[mf][nf][j] - gm);
                acc[mf][nf][j] = e;
                s += e;
            }
        s += __shfl_xor(s, 16);
        s += __shfl_xor(s, 32);
        if (lane < 16) redsum[wid * 64 + nf * 16 + lane] = s;
    }
    __syncthreads();

    // ---- normalize + transposed coalesced write: out[b][k][hw0+px] ----
    const size_t obase = (size_t)b * NPROTO * HW + hw0;
#pragma unroll
    for (int nf = 0; nf < 4; ++nf) {
        int px = nf * 16 + lcol;
        float s = 0.0f;
#pragma unroll
        for (int w = 0; w < 16; ++w) s += redsum[w * 64 + px];
        float inv = 1.0f / s;
#pragma unroll
        for (int mf = 0; mf < 4; ++mf)
#pragma unroll
            for (int j = 0; j < 4; ++j) {
                int kidx = wid * 64 + mf * 16 + lrow * 4 + j;
                out[obase + (size_t)kidx * HW + px] = acc[mf][nf][j] * inv;
            }
    }
}

// ---------------- finalize: mask = (counts > 3).sum() / 16 ----------------
__global__ void finalize(const int* __restrict__ counts, float* __restrict__ out) {
    int t = threadIdx.x;  // 256
    int local = 0;
    for (int i = t; i < NB * NPROTO; i += 256) local += (counts[i] > 3) ? 1 : 0;
#pragma unroll
    for (int m = 1; m < 64; m <<= 1) local += __shfl_xor(local, m);
    __shared__ int wsum[4];
    if ((t & 63) == 0) wsum[t >> 6] = local;
    __syncthreads();
    if (t == 0) out[(size_t)NPIX * NPROTO] = (float)(wsum[0] + wsum[1] + wsum[2] + wsum[3]) / 16.0f;
}

extern "C" void kernel_launch(void* const* d_in, const int* in_sizes, int n_in,
                              void* d_out, int out_size, void* d_ws, size_t ws_size,
                              hipStream_t stream) {
    const float* fm    = (const float*)d_in[0];   // [16][512][64][64] f32
    const float* proto = (const float*)d_in[1];   // [1][1024][512] f32
    float* out = (float*)d_out;                   // sims (67108864) + mask (1)

    char* ws = (char*)d_ws;
    _Float16* Ph     = (_Float16*)ws;                                  // 1 MB
    float*    pnorm  = (float*)(ws + (size_t)NPROTO * EMB * 2);        // 4 KB
    int*      counts = (int*)(ws + (size_t)NPROTO * EMB * 2 + 4096);   // 64 KB

    prep_protos<<<NPROTO, 64, 0, stream>>>(proto, Ph, pnorm);
    zero_counts<<<(NB * NPROTO + 255) / 256, 256, 0, stream>>>(counts);
    assign_main<<<NPIX / TPX, NTHR, 0, stream>>>(fm, Ph, pnorm, counts, out);
    finalize<<<1, 256, 0, stream>>>(counts, out);
}